// Round 1
// baseline (26.856 us; speedup 1.0000x reference)
//
#include <hip/hip_runtime.h>
#include <math.h>

// Problem constants (match reference)
#define B 8
#define N 500
#define K 16
#define D 32
#define C 16
#define T_IN 12
#define T_OUT 12

// One block per node (b,n), 256 threads.
// Phase 1: stage features row, compute k = f @ Wk + bk (32 threads).
// Phase 2: 16 groups x 16 lanes. Group g handles neighbor j = adj[b,n,g]:
//          each lane computes 2 dims of q_j, t = tanh(k+q) -> LDS;
//          lane c scores class c (32-MAC dot with Wc), softmax-replicated
//          argmax via 16-lane butterfly shuffles (first-occurrence ties).
//          Lanes 0..11 also gather input_seq[b,j,:].
// Phase 3: threads (c,t) compute masked mean over the 16 neighbors.
// Phase 4: threads (c,o) compute tanh(avg @ Wcls[c]) and store (coalesced).
__global__ __launch_bounds__(256) void embed_gcn_fused(
    const float* __restrict__ features,   // B*N*D
    const float* __restrict__ input_seq,  // B*N*T_IN
    const float* __restrict__ Wk,         // D*D
    const float* __restrict__ bk,         // D
    const float* __restrict__ Wq,         // D*D
    const float* __restrict__ bq,         // D
    const float* __restrict__ Wc,         // D*C
    const float* __restrict__ bc,         // C
    const float* __restrict__ Wcls,       // C*T_IN*T_OUT
    const int*   __restrict__ adj,        // B*N*K
    float* __restrict__ out)              // B*N*C*T_OUT
{
    const int node = blockIdx.x;          // 0..B*N-1
    const int b    = node / N;
    const int n    = node - b * N;
    const int tid  = threadIdx.x;

    __shared__ float s_feat[D];           // own features row
    __shared__ float s_k[D];              // k row (incl. bias)
    __shared__ float s_t[K][D];           // tanh(k + q_j) per neighbor
    __shared__ float s_x[K][T_IN];        // gathered input_seq rows
    __shared__ int   s_id[K];             // cluster id per neighbor
    __shared__ float s_avg[C][T_IN];      // per-class mean

    // ---- Phase 1: k = features[b,n,:] @ Wk + bk ----
    if (tid < D) s_feat[tid] = features[(size_t)(b * N + n) * D + tid];
    __syncthreads();

    if (tid < D) {
        float acc = bk[tid];
        #pragma unroll
        for (int e = 0; e < D; ++e) acc += s_feat[e] * Wk[e * D + tid];
        s_k[tid] = acc;
    }
    __syncthreads();

    // ---- Phase 2: per-neighbor q, tanh, class scores, argmax ----
    const int g = tid >> 4;               // neighbor slot 0..15
    const int c = tid & 15;               // class lane 0..15
    const int j = adj[((size_t)(b * N + n)) * K + g];

    {
        const float* fj = &features[(size_t)(b * N + j) * D];
        float acc0 = bq[c];
        float acc1 = bq[c + 16];
        #pragma unroll
        for (int e = 0; e < D; ++e) {
            const float f = fj[e];
            acc0 += f * Wq[e * D + c];
            acc1 += f * Wq[e * D + c + 16];
        }
        s_t[g][c]      = tanhf(s_k[c] + acc0);
        s_t[g][c + 16] = tanhf(s_k[c + 16] + acc1);
    }
    if (c < T_IN) s_x[g][c] = input_seq[(size_t)(b * N + j) * T_IN + c];
    __syncthreads();

    {
        float acc = bc[c];
        #pragma unroll
        for (int d = 0; d < D; ++d) acc += s_t[g][d] * Wc[d * C + c];

        // Replicate softmax rounding, then first-occurrence argmax on probs.
        float m = acc;
        #pragma unroll
        for (int off = 8; off; off >>= 1) m = fmaxf(m, __shfl_xor(m, off, 16));
        const float e = expf(acc - m);
        float sum = e;
        #pragma unroll
        for (int off = 8; off; off >>= 1) sum += __shfl_xor(sum, off, 16);
        const float p = e / sum;

        float bp = p; int bi = c;
        #pragma unroll
        for (int off = 8; off; off >>= 1) {
            const float op = __shfl_xor(bp, off, 16);
            const int   oi = __shfl_xor(bi, off, 16);
            if (op > bp || (op == bp && oi < bi)) { bp = op; bi = oi; }
        }
        if (c == 0) s_id[g] = bi;
    }
    __syncthreads();

    // ---- Phase 3: per-class masked mean over 16 neighbors ----
    if (tid < C * T_IN) {
        const int cc = tid / T_IN;
        const int t  = tid - cc * T_IN;
        float s = 0.f; int cnt = 0;
        #pragma unroll
        for (int kk = 0; kk < K; ++kk) {
            if (s_id[kk] == cc) { s += s_x[kk][t]; ++cnt; }
        }
        s_avg[cc][t] = s / (float)(cnt ? cnt : 1);
    }
    __syncthreads();

    // ---- Phase 4: out = tanh(avg @ Wcls[c]) ----
    if (tid < C * T_OUT) {
        const int cc = tid / T_OUT;
        const int o  = tid - cc * T_OUT;
        float acc = 0.f;
        #pragma unroll
        for (int t = 0; t < T_IN; ++t)
            acc += s_avg[cc][t] * Wcls[(cc * T_IN + t) * T_OUT + o];
        out[((size_t)(b * N + n) * C + cc) * T_OUT + o] = tanhf(acc);
    }
}

extern "C" void kernel_launch(void* const* d_in, const int* in_sizes, int n_in,
                              void* d_out, int out_size, void* d_ws, size_t ws_size,
                              hipStream_t stream) {
    const float* features  = (const float*)d_in[0];
    const float* input_seq = (const float*)d_in[1];
    const float* Wk        = (const float*)d_in[2];
    const float* bk        = (const float*)d_in[3];
    const float* Wq        = (const float*)d_in[4];
    const float* bq        = (const float*)d_in[5];
    const float* Wc        = (const float*)d_in[6];
    const float* bc        = (const float*)d_in[7];
    const float* Wcls      = (const float*)d_in[8];
    const int*   adj       = (const int*)d_in[9];
    float*       out       = (float*)d_out;

    embed_gcn_fused<<<B * N, 256, 0, stream>>>(
        features, input_seq, Wk, bk, Wq, bq, Wc, bc, Wcls, adj, out);
}

// Round 2
// 24.149 us; speedup vs baseline: 1.1121x; 1.1121x over previous
//
#include <hip/hip_runtime.h>
#include <math.h>

// Problem constants (match reference)
#define B 8
#define N 500
#define K 16
#define D 32
#define C 16
#define T_IN 12
#define T_OUT 12

#define NNODE (B * N)

// ---------------- Kernel 1: k,q projections for all nodes ----------------
// kq[node][0..31]  = features[node] @ Wk + bk
// kq[node][32..63] = features[node] @ Wq + bq
// Block = 256 threads = 4 nodes x 64 lanes (lane<32 -> k dim, lane>=32 -> q dim).
__global__ __launch_bounds__(256) void compute_kq(
    const float* __restrict__ features,   // NNODE*D
    const float* __restrict__ Wk,         // D*D
    const float* __restrict__ bk,         // D
    const float* __restrict__ Wq,         // D*D
    const float* __restrict__ bq,         // D
    float* __restrict__ kq)               // NNODE*64
{
    const int tid   = threadIdx.x;
    const int local = tid >> 6;           // node within block, 0..3
    const int lane  = tid & 63;
    const int node  = blockIdx.x * 4 + local;

    __shared__ float s_f[4][D];
    if (tid < 4 * D)
        s_f[tid >> 5][tid & 31] = features[(size_t)(blockIdx.x * 4 + (tid >> 5)) * D + (tid & 31)];
    __syncthreads();

    const int d    = lane & 31;
    const bool isQ = lane >= 32;
    const float* __restrict__ W = isQ ? Wq : Wk;
    float acc = isQ ? bq[d] : bk[d];
    #pragma unroll
    for (int e = 0; e < D; ++e) acc += s_f[local][e] * W[e * D + d];
    kq[(size_t)node * 64 + lane] = acc;
}

// ---------------- Kernel 2: per-node attention-cluster + GCN ----------------
// One block per node (b,n), 256 threads = 16 neighbor-groups x 16 class-lanes.
__global__ __launch_bounds__(256) void embed_gcn_fused(
    const float* __restrict__ input_seq,  // NNODE*T_IN
    const float* __restrict__ Wc,         // D*C
    const float* __restrict__ bc,         // C
    const float* __restrict__ Wcls,       // C*T_IN*T_OUT
    const int*   __restrict__ adj,        // NNODE*K
    const float* __restrict__ kq,         // NNODE*64 (from kernel 1)
    float* __restrict__ out)              // NNODE*C*T_OUT
{
    const int node = blockIdx.x;          // 0..NNODE-1
    const int b    = node / N;
    const int tid  = threadIdx.x;

    __shared__ float s_k[D];              // own k row
    __shared__ float s_Wc[D * C];         // staged Wc
    __shared__ float s_bc[C];
    __shared__ float s_t[K][D + 1];       // tanh(k + q_j), padded (bank)
    __shared__ float s_x[K][T_IN];        // gathered input_seq rows
    __shared__ int   s_id[K];             // cluster id per neighbor
    __shared__ float s_avg[C][T_IN];      // per-class mean

    // ---- Stage: own k, Wc, bc ----
    if (tid < D) s_k[tid] = kq[(size_t)node * 64 + tid];
    s_Wc[tid]       = Wc[tid];
    s_Wc[tid + 256] = Wc[tid + 256];
    if (tid < C) s_bc[tid] = bc[tid];

    // ---- Phase 2a: per-neighbor tanh(k+q) + x gather ----
    const int g = tid >> 4;               // neighbor slot 0..15
    const int c = tid & 15;               // class lane 0..15
    const int j = adj[(size_t)node * K + g];
    const float* __restrict__ qj = &kq[((size_t)(b * N + j)) * 64 + 32];
    const float q0 = qj[c];
    const float q1 = qj[c + 16];
    __syncthreads();                      // s_k ready

    s_t[g][c]      = tanhf(s_k[c] + q0);
    s_t[g][c + 16] = tanhf(s_k[c + 16] + q1);
    if (c < T_IN) s_x[g][c] = input_seq[(size_t)(b * N + j) * T_IN + c];
    __syncthreads();

    // ---- Phase 2b: class scores, softmax-replicated argmax ----
    {
        float acc = s_bc[c];
        #pragma unroll
        for (int d = 0; d < D; ++d) acc += s_t[g][d] * s_Wc[d * C + c];

        float m = acc;
        #pragma unroll
        for (int off = 8; off; off >>= 1) m = fmaxf(m, __shfl_xor(m, off, 16));
        const float e = expf(acc - m);
        float sum = e;
        #pragma unroll
        for (int off = 8; off; off >>= 1) sum += __shfl_xor(sum, off, 16);
        const float p = e / sum;

        float bp = p; int bi = c;
        #pragma unroll
        for (int off = 8; off; off >>= 1) {
            const float op = __shfl_xor(bp, off, 16);
            const int   oi = __shfl_xor(bi, off, 16);
            if (op > bp || (op == bp && oi < bi)) { bp = op; bi = oi; }
        }
        if (c == 0) s_id[g] = bi;
    }
    __syncthreads();

    // ---- Phase 3: per-class masked mean over 16 neighbors ----
    if (tid < C * T_IN) {
        const int cc = tid / T_IN;
        const int t  = tid - cc * T_IN;
        float s = 0.f; int cnt = 0;
        #pragma unroll
        for (int kk = 0; kk < K; ++kk) {
            if (s_id[kk] == cc) { s += s_x[kk][t]; ++cnt; }
        }
        s_avg[cc][t] = s / (float)(cnt ? cnt : 1);
    }
    __syncthreads();

    // ---- Phase 4: out = tanh(avg @ Wcls[c]) ----
    if (tid < C * T_OUT) {
        const int cc = tid / T_OUT;
        const int o  = tid - cc * T_OUT;
        float acc = 0.f;
        #pragma unroll
        for (int t = 0; t < T_IN; ++t)
            acc += s_avg[cc][t] * Wcls[(cc * T_IN + t) * T_OUT + o];
        out[((size_t)node * C + cc) * T_OUT + o] = tanhf(acc);
    }
}

extern "C" void kernel_launch(void* const* d_in, const int* in_sizes, int n_in,
                              void* d_out, int out_size, void* d_ws, size_t ws_size,
                              hipStream_t stream) {
    const float* features  = (const float*)d_in[0];
    const float* input_seq = (const float*)d_in[1];
    const float* Wk        = (const float*)d_in[2];
    const float* bk        = (const float*)d_in[3];
    const float* Wq        = (const float*)d_in[4];
    const float* bq        = (const float*)d_in[5];
    const float* Wc        = (const float*)d_in[6];
    const float* bc        = (const float*)d_in[7];
    const float* Wcls      = (const float*)d_in[8];
    const int*   adj       = (const int*)d_in[9];
    float*       out       = (float*)d_out;
    float*       kq        = (float*)d_ws;     // NNODE*64 floats = 1 MB

    compute_kq<<<NNODE / 4, 256, 0, stream>>>(features, Wk, bk, Wq, bq, kq);
    embed_gcn_fused<<<NNODE, 256, 0, stream>>>(input_seq, Wc, bc, Wcls, adj, kq, out);
}

// Round 3
// 19.173 us; speedup vs baseline: 1.4007x; 1.2595x over previous
//
#include <hip/hip_runtime.h>
#include <math.h>

// Problem constants (match reference)
#define B 8
#define N 500
#define K 16
#define D 32
#define C 16
#define T_IN 12
#define T_OUT 12
#define NNODE (B * N)

// ---------------- Kernel 1: k,q projections for all nodes ----------------
// kq[node][0..31]  = features[node] @ Wk + bk
// kq[node][32..63] = features[node] @ Wq + bq
// Block = 256 threads = 4 nodes x 64 lanes; Wk/Wq staged in LDS.
__global__ __launch_bounds__(256) void compute_kq(
    const float* __restrict__ features,   // NNODE*D
    const float* __restrict__ Wk,         // D*D
    const float* __restrict__ bk,         // D
    const float* __restrict__ Wq,         // D*D
    const float* __restrict__ bq,         // D
    float* __restrict__ kq)               // NNODE*64
{
    const int tid = threadIdx.x;
    __shared__ float s_W[2][D * D];       // [0]=Wk, [1]=Wq
    __shared__ float s_b[2][D];
    __shared__ float s_f[4][D];

    #pragma unroll
    for (int i = 0; i < 4; ++i) s_W[0][tid + i * 256] = Wk[tid + i * 256];
    #pragma unroll
    for (int i = 0; i < 4; ++i) s_W[1][tid + i * 256] = Wq[tid + i * 256];
    if (tid < D) { s_b[0][tid] = bk[tid]; s_b[1][tid] = bq[tid]; }
    if (tid < 4 * D)
        s_f[tid >> 5][tid & 31] =
            features[(size_t)(blockIdx.x * 4 + (tid >> 5)) * D + (tid & 31)];
    __syncthreads();

    const int local = tid >> 6;           // node within block
    const int lane  = tid & 63;
    const int d     = lane & 31;
    const int m     = lane >> 5;          // 0 = k, 1 = q
    float acc = s_b[m][d];
    #pragma unroll
    for (int e = 0; e < D; ++e) acc += s_f[local][e] * s_W[m][e * D + d];
    kq[(size_t)(blockIdx.x * 4 + local) * 64 + lane] = acc;
}

// ---------------- Kernel 2: wave-per-node attention-cluster + GCN ----------
// Block = 256 threads = 4 waves; wave w owns node = blockIdx.x*4 + w.
// Lane l: subgroup s = l&3 (4 class-slots / 8 q-dims each), neighbor g = l>>2.
__global__ __launch_bounds__(256) void embed_gcn_fused(
    const float* __restrict__ input_seq,  // NNODE*T_IN
    const float* __restrict__ Wc,         // D*C
    const float* __restrict__ bc,         // C
    const float* __restrict__ Wcls,       // C*T_IN*T_OUT
    const int*   __restrict__ adj,        // NNODE*K
    const float* __restrict__ kq,         // NNODE*64 (from kernel 1)
    float* __restrict__ out)              // NNODE*C*T_OUT
{
    const int tid  = threadIdx.x;
    const int w    = tid >> 6;            // wave in block
    const int l    = tid & 63;
    const int s    = l & 3;
    const int g    = l >> 2;              // neighbor slot 0..15
    const int node = blockIdx.x * 4 + w;
    const int b    = node / N;

    __shared__ __align__(16) float s_Wc[D * C];             // 512
    __shared__ __align__(16) float s_Wcls[C * T_IN * T_OUT];// 2304
    __shared__ float s_bc[C];
    __shared__ __align__(16) float s_k[4][D];
    __shared__ __align__(16) float s_t[4][K][36];           // padded
    __shared__ __align__(16) float s_x[4][K][T_IN];
    __shared__ float s_avg[4][C][T_IN];
    __shared__ int   s_id[4][K];
    __shared__ int   s_adj[4][K];

    // ---- Stage shared weights + per-wave adj/k ----
    s_Wc[tid]       = Wc[tid];
    s_Wc[tid + 256] = Wc[tid + 256];
    #pragma unroll
    for (int i = 0; i < 9; ++i) s_Wcls[tid + i * 256] = Wcls[tid + i * 256];
    if (tid < C) s_bc[tid] = bc[tid];
    if (l < K) s_adj[w][l] = adj[(size_t)node * K + l];
    if (l < D) s_k[w][l] = kq[(size_t)node * 64 + l];
    __syncthreads();

    // ---- Phase B: per-neighbor tanh(k+q) + x gather ----
    const int j  = s_adj[w][g];
    const int jn = b * N + j;
    const float4 q0 = *(const float4*)&kq[(size_t)jn * 64 + 32 + s * 8];
    const float4 q1 = *(const float4*)&kq[(size_t)jn * 64 + 32 + s * 8 + 4];
    float4 x4;
    if (s < 3) x4 = *(const float4*)&input_seq[(size_t)jn * T_IN + s * 4];
    const float4 k0 = *(const float4*)&s_k[w][s * 8];
    const float4 k1 = *(const float4*)&s_k[w][s * 8 + 4];

    float4 t0, t1;
    t0.x = tanhf(k0.x + q0.x);  t0.y = tanhf(k0.y + q0.y);
    t0.z = tanhf(k0.z + q0.z);  t0.w = tanhf(k0.w + q0.w);
    t1.x = tanhf(k1.x + q1.x);  t1.y = tanhf(k1.y + q1.y);
    t1.z = tanhf(k1.z + q1.z);  t1.w = tanhf(k1.w + q1.w);
    *(float4*)&s_t[w][g][s * 8]     = t0;
    *(float4*)&s_t[w][g][s * 8 + 4] = t1;
    if (s < 3) *(float4*)&s_x[w][g][s * 4] = x4;
    __syncthreads();

    // ---- Phase C: class scores (lane s owns classes s*4..s*4+3) ----
    float a0 = s_bc[s * 4 + 0];
    float a1 = s_bc[s * 4 + 1];
    float a2 = s_bc[s * 4 + 2];
    float a3 = s_bc[s * 4 + 3];
    #pragma unroll
    for (int ch = 0; ch < 8; ++ch) {
        const float4 t4 = *(const float4*)&s_t[w][g][ch * 4];
        const float tv[4] = { t4.x, t4.y, t4.z, t4.w };
        #pragma unroll
        for (int dd = 0; dd < 4; ++dd) {
            const int d = ch * 4 + dd;
            const float4 w4 = *(const float4*)&s_Wc[d * C + s * 4];
            a0 += tv[dd] * w4.x;
            a1 += tv[dd] * w4.y;
            a2 += tv[dd] * w4.z;
            a3 += tv[dd] * w4.w;
        }
    }

    // softmax-replicated argmax over 16 classes (4 lanes x 4 local)
    float m = fmaxf(fmaxf(a0, a1), fmaxf(a2, a3));
    m = fmaxf(m, __shfl_xor(m, 1, 4));
    m = fmaxf(m, __shfl_xor(m, 2, 4));
    const float e0 = expf(a0 - m), e1 = expf(a1 - m);
    const float e2 = expf(a2 - m), e3 = expf(a3 - m);
    float sum = e0 + e1 + e2 + e3;
    sum += __shfl_xor(sum, 1, 4);
    sum += __shfl_xor(sum, 2, 4);
    const float p0 = e0 / sum, p1 = e1 / sum, p2 = e2 / sum, p3 = e3 / sum;

    float bp = p0; int bi = s * 4;
    if (p1 > bp) { bp = p1; bi = s * 4 + 1; }
    if (p2 > bp) { bp = p2; bi = s * 4 + 2; }
    if (p3 > bp) { bp = p3; bi = s * 4 + 3; }
    #pragma unroll
    for (int off = 1; off <= 2; off <<= 1) {
        const float op = __shfl_xor(bp, off, 4);
        const int   oi = __shfl_xor(bi, off, 4);
        if (op > bp || (op == bp && oi < bi)) { bp = op; bi = oi; }
    }
    if (s == 0) s_id[w][g] = bi;
    __syncthreads();

    // ---- Phase E: per-class masked mean (192 tasks, 3 per lane) ----
    int ids[K];
    #pragma unroll
    for (int kk = 0; kk < K; ++kk) ids[kk] = s_id[w][kk];
    #pragma unroll
    for (int it = 0; it < 3; ++it) {
        const int id2 = l + it * 64;        // 0..191
        const int cc  = id2 / T_IN;
        const int t   = id2 - cc * T_IN;
        float sm = 0.f; int cnt = 0;
        #pragma unroll
        for (int kk = 0; kk < K; ++kk) {
            const bool hit = (ids[kk] == cc);
            const float xv = s_x[w][kk][t];
            if (hit) { sm += xv; ++cnt; }
        }
        s_avg[w][cc][t] = sm / (float)(cnt ? cnt : 1);
    }
    __syncthreads();

    // ---- Phase F: out = tanh(avg @ Wcls[cc]) (192 tasks, 3 per lane) ----
    #pragma unroll
    for (int it = 0; it < 3; ++it) {
        const int id2 = l + it * 64;        // 0..191  == cc*12 + o
        const int cc  = id2 / T_OUT;
        const int o   = id2 - cc * T_OUT;
        float acc = 0.f;
        #pragma unroll
        for (int t = 0; t < T_IN; ++t)
            acc += s_avg[w][cc][t] * s_Wcls[cc * (T_IN * T_OUT) + t * T_OUT + o];
        out[(size_t)node * (C * T_OUT) + id2] = tanhf(acc);
    }
}

extern "C" void kernel_launch(void* const* d_in, const int* in_sizes, int n_in,
                              void* d_out, int out_size, void* d_ws, size_t ws_size,
                              hipStream_t stream) {
    const float* features  = (const float*)d_in[0];
    const float* input_seq = (const float*)d_in[1];
    const float* Wk        = (const float*)d_in[2];
    const float* bk        = (const float*)d_in[3];
    const float* Wq        = (const float*)d_in[4];
    const float* bq        = (const float*)d_in[5];
    const float* Wc        = (const float*)d_in[6];
    const float* bc        = (const float*)d_in[7];
    const float* Wcls      = (const float*)d_in[8];
    const int*   adj       = (const int*)d_in[9];
    float*       out       = (float*)d_out;
    float*       kq        = (float*)d_ws;     // NNODE*64 floats = 1 MB

    compute_kq<<<NNODE / 4, 256, 0, stream>>>(features, Wk, bk, Wq, bq, kq);
    embed_gcn_fused<<<NNODE / 4, 256, 0, stream>>>(input_seq, Wc, bc, Wcls, adj, kq, out);
}